// Round 6
// baseline (1721.796 us; speedup 1.0000x reference)
//
#include <hip/hip_runtime.h>
#include <hip/hip_bf16.h>

// GCN 2-layer on MI355X — global-atomic-free pipeline.
// R5 post-mortem: global atomicAdd-with-return is walled at ~24 ops/ns device-
// wide regardless of contention (4x shadows) or ILP (16-way) -> eliminate it.
// New: bucket edges by dst>>7 (782 buckets x 128 nodes) via radix-pass
// (LDS hist -> global scan of hist[bucket][block] -> LDS-rank partition).
// Aggregation: block-per-bucket, LDS f32 acc[128][64], ds_add_f32 only.
// hb stores bf16(h * dinv[row]) so aggB needs no dinv[src] gather.

__device__ __forceinline__ float bf2f(unsigned short u) {
    union { unsigned int u; float f; } c; c.u = ((unsigned int)u) << 16; return c.f;
}
__device__ __forceinline__ unsigned short f2bf(float f) {
    union { float f; unsigned int u; } c; c.f = f;
    unsigned int u = c.u;
    unsigned int r = (u + 0x7fffu + ((u >> 16) & 1u)) >> 16;  // round-nearest-even
    return (unsigned short)r;
}
__device__ __forceinline__ float loadF(const void* p, int i, int isbf) {
    return isbf ? bf2f(((const unsigned short*)p)[i]) : ((const float*)p)[i];
}
__device__ __forceinline__ int edgeIdx(const void* e, long long i, int is64) {
    return is64 ? (int)((const long long*)e)[i] : ((const int*)e)[i];
}

// flags[0] = edge indices are int64; flags[1] = float tensors are bf16
__global__ void k_detect(const void* e, const void* x, int* flags) {
    int lane = threadIdx.x;  // blockDim = 64
    unsigned int ew = ((const unsigned int*)e)[2 * lane + 1];
    unsigned long long nz = __ballot(ew != 0);
    unsigned int xw = ((const unsigned int*)x)[lane];
    unsigned int low = xw & 0xffffu;
    unsigned int e8 = (low >> 7) & 0xffu;
    bool plaus = (low == 0u) || (e8 >= 110u && e8 <= 135u);
    unsigned long long pl = __ballot(plaus);
    if (lane == 0) {
        flags[0] = (nz == 0ull) ? 1 : 0;
        flags[1] = (__popcll(pl) > 32) ? 1 : 0;
    }
}

// Per-block LDS histogram over B coarse buckets; write hist[bucket][block]
// (bucket-major) fully, so no global memset needed. 4096 edges/block.
__launch_bounds__(256)
__global__ void k_hist(const void* e, int* __restrict__ histT, const int* flags,
                       int E, int B, int HB) {
    __shared__ int hist[1024];
    int tid = threadIdx.x;
    int is64 = flags[0];
    for (int f = tid; f < B; f += 256) hist[f] = 0;
    __syncthreads();
    int base = blockIdx.x * 4096;
    #pragma unroll
    for (int k = 0; k < 16; ++k) {
        int i = base + k * 256 + tid;
        if (i < E) {
            int d = edgeIdx(e, (long long)E + i, is64);
            atomicAdd(&hist[d >> 7], 1);   // LDS atomic
        }
    }
    __syncthreads();
    for (int f = tid; f < B; f += 256)
        histT[(long long)f * HB + blockIdx.x] = hist[f];
}

// Exclusive scan over M = B*HB ints, level A (in-place within 256-blocks).
__global__ void k_scanA(int* __restrict__ data, int* __restrict__ partial, int M) {
    __shared__ int s[256];
    int tid = threadIdx.x;
    int i = blockIdx.x * 256 + tid;
    int v = (i < M) ? data[i] : 0;
    s[tid] = v; __syncthreads();
    for (int off = 1; off < 256; off <<= 1) {
        int t = (tid >= off) ? s[tid - off] : 0;
        __syncthreads(); s[tid] += t; __syncthreads();
    }
    if (i < M) data[i] = s[tid] - v;
    if (tid == 255) partial[blockIdx.x] = s[255];
}

// Level B: in-place exclusive scan of nP partials. 1024 threads, C<=8 each.
__global__ void k_scanB(int* __restrict__ partial, int nP) {
    __shared__ int s[1024];
    int tid = threadIdx.x;
    int C = (nP + 1023) >> 10;
    int base = tid * C;
    int v[8]; int tot = 0;
    for (int j = 0; j < C; ++j) { v[j] = (base + j < nP) ? partial[base + j] : 0; tot += v[j]; }
    s[tid] = tot; __syncthreads();
    for (int off = 1; off < 1024; off <<= 1) {
        int t = (tid >= off) ? s[tid - off] : 0;
        __syncthreads(); s[tid] += t; __syncthreads();
    }
    int run = s[tid] - tot;
    for (int j = 0; j < C; ++j) { if (base + j < nP) { int tmp = v[j]; partial[base + j] = run; run += tmp; } }
}

// Level C: add block bases; extract bucketStart[b] = prefix at (b, blk=0).
__global__ void k_scanC(int* __restrict__ data, const int* __restrict__ partial,
                        int* __restrict__ bucketStart, int M, int HB, int B, int E) {
    int f = blockIdx.x * 256 + threadIdx.x;
    if (f < M) {
        int val = data[f] + partial[f >> 8];
        data[f] = val;
        int q = f / HB;
        if (f - q * HB == 0) bucketStart[q] = val;
    }
    if (f == 0) bucketStart[B] = E;
}

// Partition: pos = scanned[bucket][block] + LDS-atomic rank. No global atomics.
// part[pos] = src | (dstLocal << 20)   (requires N < 2^20).
__launch_bounds__(256)
__global__ void k_part(const void* e, const int* __restrict__ histT,
                       int* __restrict__ part, const int* flags,
                       int E, int B, int HB) {
    __shared__ int lcur[1024];
    int tid = threadIdx.x;
    int is64 = flags[0];
    for (int f = tid; f < B; f += 256)
        lcur[f] = histT[(long long)f * HB + blockIdx.x];
    __syncthreads();
    int base = blockIdx.x * 4096;
    #pragma unroll
    for (int k = 0; k < 16; ++k) {
        int i = base + k * 256 + tid;
        if (i < E) {
            int s = edgeIdx(e, i, is64);
            int d = edgeIdx(e, (long long)E + i, is64);
            int pos = atomicAdd(&lcur[d >> 7], 1);   // LDS atomic
            part[pos] = s | ((d & 127) << 20);
        }
    }
}

// Per-bucket exact degree -> dinv. Block per bucket, 128 LDS counters.
__launch_bounds__(256)
__global__ void k_deg(const int* __restrict__ part, const int* __restrict__ bucketStart,
                      float* __restrict__ dinv, int N) {
    __shared__ int cnt[128];
    int tid = threadIdx.x, b = blockIdx.x;
    if (tid < 128) cnt[tid] = 0;
    __syncthreads();
    int lo = bucketStart[b], hi = bucketStart[b + 1];
    for (int idx = lo + tid; idx < hi; idx += 256)
        atomicAdd(&cnt[(part[idx] >> 20) & 127], 1);
    __syncthreads();
    if (tid < 128) {
        int node = b * 128 + tid;
        if (node < N) dinv[node] = rsqrtf((float)(cnt[tid] + 1));  // +1 self-loop
    }
}

// hb[row][lane] = bf16( (x@W1)[row][lane] * dinv[row] )  — src-norm folded in.
__launch_bounds__(256)
__global__ void k_gemm(const void* x, const void* W1, const float* __restrict__ dinv,
                       unsigned short* __restrict__ hb, const int* flags, int N) {
    __shared__ float Wl[128 * 64];   // 32 KB
    __shared__ float xr[4][128];
    int tid = threadIdx.x;
    int isbf = flags[1];
    for (int idx = tid; idx < 128 * 64; idx += 256) Wl[idx] = loadF(W1, idx, isbf);
    int w = tid >> 6, lane = tid & 63;
    for (int rb = blockIdx.x * 4; rb < N; rb += gridDim.x * 4) {
        int row = rb + w;
        bool active = row < N;
        __syncthreads();
        if (active) {
            if (isbf) {
                unsigned int wv = ((const unsigned int*)x)[(long long)row * 64 + lane];
                xr[w][2 * lane]     = bf2f((unsigned short)(wv & 0xffffu));
                xr[w][2 * lane + 1] = bf2f((unsigned short)(wv >> 16));
            } else {
                xr[w][lane]      = ((const float*)x)[(long long)row * 128 + lane];
                xr[w][lane + 64] = ((const float*)x)[(long long)row * 128 + 64 + lane];
            }
        }
        __syncthreads();
        if (active) {
            float acc = 0.f;
            #pragma unroll
            for (int k = 0; k < 128; ++k)
                acc += xr[w][k] * Wl[k * 64 + lane];
            hb[(long long)row * 64 + lane] = f2bf(acc * dinv[row]);
        }
    }
}

// Layer-1 aggregation, block per bucket. LDS f32 acc[128][64]; edge-parallel
// waves with 8-way-batched gathers; ds_add_f32 (wave-uniform row, lane col ->
// conflict-free). Fused epilogue: +b1, relu, dot W2, *dinv -> sbuf2.
__launch_bounds__(256)
__global__ void k_aggB(const unsigned short* __restrict__ hb, const int* __restrict__ part,
                       const int* __restrict__ bucketStart, const float* __restrict__ dinv,
                       const void* b1, const void* W2, float* __restrict__ sbuf2,
                       const int* flags, int N) {
    __shared__ float acc[128][64];   // 32 KB
    __shared__ float dloc[128];
    int tid = threadIdx.x, b = blockIdx.x;
    int w = tid >> 6, lane = tid & 63;
    int isbf = flags[1];
    if (tid < 128) {
        int node = b * 128 + tid;
        dloc[tid] = (node < N) ? dinv[node] : 0.f;
    }
    __syncthreads();
    // self-loop init: hb already holds h*dinv[node]; one more dloc factor.
    for (int j = w; j < 128; j += 4) {
        int node = b * 128 + j;
        acc[j][lane] = (node < N) ? bf2f(hb[(long long)node * 64 + lane]) * dloc[j] : 0.f;
    }
    __syncthreads();
    int lo = bucketStart[b], hi = bucketStart[b + 1];
    for (int cs = lo + w * 64; cs < hi; cs += 256) {
        int t = cs + lane;
        int pw = 0; float wv = 0.f;
        if (t < hi) { pw = part[t]; wv = dloc[(pw >> 20) & 127]; }
        int m = hi - cs; if (m > 64) m = 64;
        int t2 = 0;
        for (; t2 + 8 <= m; t2 += 8) {
            int p0 = __shfl(pw, t2 + 0), p1 = __shfl(pw, t2 + 1);
            int p2 = __shfl(pw, t2 + 2), p3 = __shfl(pw, t2 + 3);
            int p4 = __shfl(pw, t2 + 4), p5 = __shfl(pw, t2 + 5);
            int p6 = __shfl(pw, t2 + 6), p7 = __shfl(pw, t2 + 7);
            float w0 = __shfl(wv, t2 + 0), w1 = __shfl(wv, t2 + 1);
            float w2 = __shfl(wv, t2 + 2), w3 = __shfl(wv, t2 + 3);
            float w4 = __shfl(wv, t2 + 4), w5 = __shfl(wv, t2 + 5);
            float w6 = __shfl(wv, t2 + 6), w7 = __shfl(wv, t2 + 7);
            unsigned short v0 = hb[(long long)(p0 & 0xFFFFF) * 64 + lane];
            unsigned short v1 = hb[(long long)(p1 & 0xFFFFF) * 64 + lane];
            unsigned short v2 = hb[(long long)(p2 & 0xFFFFF) * 64 + lane];
            unsigned short v3 = hb[(long long)(p3 & 0xFFFFF) * 64 + lane];
            unsigned short v4 = hb[(long long)(p4 & 0xFFFFF) * 64 + lane];
            unsigned short v5 = hb[(long long)(p5 & 0xFFFFF) * 64 + lane];
            unsigned short v6 = hb[(long long)(p6 & 0xFFFFF) * 64 + lane];
            unsigned short v7 = hb[(long long)(p7 & 0xFFFFF) * 64 + lane];
            atomicAdd(&acc[(p0 >> 20) & 127][lane], bf2f(v0) * w0);
            atomicAdd(&acc[(p1 >> 20) & 127][lane], bf2f(v1) * w1);
            atomicAdd(&acc[(p2 >> 20) & 127][lane], bf2f(v2) * w2);
            atomicAdd(&acc[(p3 >> 20) & 127][lane], bf2f(v3) * w3);
            atomicAdd(&acc[(p4 >> 20) & 127][lane], bf2f(v4) * w4);
            atomicAdd(&acc[(p5 >> 20) & 127][lane], bf2f(v5) * w5);
            atomicAdd(&acc[(p6 >> 20) & 127][lane], bf2f(v6) * w6);
            atomicAdd(&acc[(p7 >> 20) & 127][lane], bf2f(v7) * w7);
        }
        for (; t2 < m; ++t2) {
            int p0 = __shfl(pw, t2);
            float w0 = __shfl(wv, t2);
            unsigned short v0 = hb[(long long)(p0 & 0xFFFFF) * 64 + lane];
            atomicAdd(&acc[(p0 >> 20) & 127][lane], bf2f(v0) * w0);
        }
    }
    __syncthreads();
    float bb = loadF(b1, lane, isbf);
    float ww = loadF(W2, lane, isbf);
    for (int j = w; j < 128; j += 4) {
        int node = b * 128 + j;
        if (node < N) {
            float v = fmaxf(acc[j][lane] + bb, 0.f);
            float p = v * ww;
            #pragma unroll
            for (int o = 32; o >= 1; o >>= 1) p += __shfl_xor(p, o);
            if (lane == 0) sbuf2[node] = p * dloc[j];
        }
    }
}

// Layer-2 scalar aggregation per bucket: acc2[dl] += sbuf2[src]; 4-way ILP.
// out[node] = (acc2 + sbuf2[node]) * dinv[node] + b2.
__launch_bounds__(256)
__global__ void k_agg2B(const int* __restrict__ part, const int* __restrict__ bucketStart,
                        const float* __restrict__ sbuf2, const float* __restrict__ dinv,
                        const void* b2, void* out, const int* flags, int N) {
    __shared__ float acc2[128];
    int tid = threadIdx.x, b = blockIdx.x;
    int isbf = flags[1];
    if (tid < 128) acc2[tid] = 0.f;
    __syncthreads();
    int lo = bucketStart[b], hi = bucketStart[b + 1];
    int idx = lo + tid;
    for (; idx + 768 < hi; idx += 1024) {
        int p0 = part[idx], p1 = part[idx + 256], p2 = part[idx + 512], p3 = part[idx + 768];
        float v0 = sbuf2[p0 & 0xFFFFF], v1 = sbuf2[p1 & 0xFFFFF];
        float v2 = sbuf2[p2 & 0xFFFFF], v3 = sbuf2[p3 & 0xFFFFF];
        atomicAdd(&acc2[(p0 >> 20) & 127], v0);
        atomicAdd(&acc2[(p1 >> 20) & 127], v1);
        atomicAdd(&acc2[(p2 >> 20) & 127], v2);
        atomicAdd(&acc2[(p3 >> 20) & 127], v3);
    }
    for (; idx < hi; idx += 256) {
        int pw = part[idx];
        atomicAdd(&acc2[(pw >> 20) & 127], sbuf2[pw & 0xFFFFF]);
    }
    __syncthreads();
    if (tid < 128) {
        int node = b * 128 + tid;
        if (node < N) {
            float o_ = (acc2[tid] + sbuf2[node]) * dinv[node] + loadF(b2, 0, isbf);
            if (isbf) ((unsigned short*)out)[node] = f2bf(o_);
            else      ((float*)out)[node] = o_;
        }
    }
}

extern "C" void kernel_launch(void* const* d_in, const int* in_sizes, int n_in,
                              void* d_out, int out_size, void* d_ws, size_t ws_size,
                              hipStream_t stream) {
    const void* x  = d_in[0];
    const void* e  = d_in[1];
    const void* W1 = d_in[2];
    const void* b1 = d_in[3];
    const void* W2 = d_in[4];
    const void* b2 = d_in[5];
    int N = in_sizes[0] / 128;     // 100000
    int E = in_sizes[1] / 2;       // 3200000
    int B  = (N + 127) / 128;      // 782 buckets (<=1024 required)
    int HB = (E + 4095) / 4096;    // 782 hist blocks
    int M  = B * HB;               // 611,524
    int nP = (M + 255) / 256;      // 2389 (<=8192 for scanB C<=8)

    // Workspace (~29 MB; R1 proved 40.4 MB safe):
    int*   wsI         = (int*)d_ws;
    int*   flags       = wsI;                          // 256
    int*   histT       = wsI + 256;                    // M (rounded)
    int*   partial     = histT + ((M + 255) / 256) * 256;  // nP (rounded)
    int*   bucketStart = partial + ((nP + 255) / 256) * 256;  // B+1 -> 1040
    float* dinv        = (float*)(bucketStart + 1040); // B*128
    float* sbuf2       = dinv + B * 128;               // B*128
    int*   part        = (int*)(sbuf2 + B * 128);      // E
    unsigned short* hb = (unsigned short*)(part + E);  // N*64 bf16 (12.8 MB)

    hipLaunchKernelGGL(k_detect, dim3(1), dim3(64), 0, stream, e, x, flags);
    hipLaunchKernelGGL(k_hist, dim3(HB), dim3(256), 0, stream, e, histT, flags, E, B, HB);
    hipLaunchKernelGGL(k_scanA, dim3(nP), dim3(256), 0, stream, histT, partial, M);
    hipLaunchKernelGGL(k_scanB, dim3(1), dim3(1024), 0, stream, partial, nP);
    hipLaunchKernelGGL(k_scanC, dim3(nP), dim3(256), 0, stream,
                       histT, partial, bucketStart, M, HB, B, E);
    hipLaunchKernelGGL(k_part, dim3(HB), dim3(256), 0, stream, e, histT, part, flags, E, B, HB);
    hipLaunchKernelGGL(k_deg, dim3(B), dim3(256), 0, stream, part, bucketStart, dinv, N);
    hipLaunchKernelGGL(k_gemm, dim3(2048), dim3(256), 0, stream, x, W1, dinv, hb, flags, N);
    hipLaunchKernelGGL(k_aggB, dim3(B), dim3(256), 0, stream,
                       hb, part, bucketStart, dinv, b1, W2, sbuf2, flags, N);
    hipLaunchKernelGGL(k_agg2B, dim3(B), dim3(256), 0, stream,
                       part, bucketStart, sbuf2, dinv, b2, d_out, flags, N);
}

// Round 8
// 382.124 us; speedup vs baseline: 4.5059x; 4.5059x over previous
//
#include <hip/hip_runtime.h>
#include <hip/hip_bf16.h>

// GCN 2-layer on MI355X — global-atomic-free CSR build + register-acc aggregation.
// R5: global atomicAdd walled at ~24 ops/ns device-wide -> no global atomics.
// R6: bucketed LDS-atomic aggregation FAILED (1450us): 782 blocks = no TLP, and
//     in-order LDS pipe serialized shfl/ds_add/gather per batch.
// R7: partition (hist->scan->part) + block-local bucket sort -> dst-sorted CSR
//     -> R4-style wave-per-node register-acc aggregation. hb = bf16(h*dinv[src])
//     folded in GEMM (edge weight becomes wave-uniform).
// R8: R7 failed absmax 1.97e-2 = self-loop algebra bug: acc init had an extra
//     *di (h*di^3 instead of h*di^2) after the dinv-fold into hb. Fixed: init
//     acc = hb[node] (epilogue's *di supplies the second factor).

__device__ __forceinline__ float bf2f(unsigned short u) {
    union { unsigned int u; float f; } c; c.u = ((unsigned int)u) << 16; return c.f;
}
__device__ __forceinline__ unsigned short f2bf(float f) {
    union { float f; unsigned int u; } c; c.f = f;
    unsigned int u = c.u;
    unsigned int r = (u + 0x7fffu + ((u >> 16) & 1u)) >> 16;  // round-nearest-even
    return (unsigned short)r;
}
__device__ __forceinline__ float loadF(const void* p, int i, int isbf) {
    return isbf ? bf2f(((const unsigned short*)p)[i]) : ((const float*)p)[i];
}
__device__ __forceinline__ int edgeIdx(const void* e, long long i, int is64) {
    return is64 ? (int)((const long long*)e)[i] : ((const int*)e)[i];
}

// flags[0] = edge indices are int64; flags[1] = float tensors are bf16
__global__ void k_detect(const void* e, const void* x, int* flags) {
    int lane = threadIdx.x;  // blockDim = 64
    unsigned int ew = ((const unsigned int*)e)[2 * lane + 1];
    unsigned long long nz = __ballot(ew != 0);
    unsigned int xw = ((const unsigned int*)x)[lane];
    unsigned int low = xw & 0xffffu;
    unsigned int e8 = (low >> 7) & 0xffu;
    bool plaus = (low == 0u) || (e8 >= 110u && e8 <= 135u);
    unsigned long long pl = __ballot(plaus);
    if (lane == 0) {
        flags[0] = (nz == 0ull) ? 1 : 0;
        flags[1] = (__popcll(pl) > 32) ? 1 : 0;
    }
}

// Per-block LDS histogram over B coarse buckets (dst>>7); hist[bucket][block].
__launch_bounds__(256)
__global__ void k_hist(const void* e, int* __restrict__ histT, const int* flags,
                       int E, int B, int HB) {
    __shared__ int hist[1024];
    int tid = threadIdx.x;
    int is64 = flags[0];
    for (int f = tid; f < B; f += 256) hist[f] = 0;
    __syncthreads();
    int base = blockIdx.x * 4096;
    #pragma unroll
    for (int k = 0; k < 16; ++k) {
        int i = base + k * 256 + tid;
        if (i < E) {
            int d = edgeIdx(e, (long long)E + i, is64);
            atomicAdd(&hist[d >> 7], 1);   // LDS atomic
        }
    }
    __syncthreads();
    for (int f = tid; f < B; f += 256)
        histT[(long long)f * HB + blockIdx.x] = hist[f];
}

// Exclusive scan over M = B*HB ints, level A.
__global__ void k_scanA(int* __restrict__ data, int* __restrict__ partial, int M) {
    __shared__ int s[256];
    int tid = threadIdx.x;
    int i = blockIdx.x * 256 + tid;
    int v = (i < M) ? data[i] : 0;
    s[tid] = v; __syncthreads();
    for (int off = 1; off < 256; off <<= 1) {
        int t = (tid >= off) ? s[tid - off] : 0;
        __syncthreads(); s[tid] += t; __syncthreads();
    }
    if (i < M) data[i] = s[tid] - v;
    if (tid == 255) partial[blockIdx.x] = s[255];
}

// Level B: in-place exclusive scan of nP partials (nP <= 8192).
__global__ void k_scanB(int* __restrict__ partial, int nP) {
    __shared__ int s[1024];
    int tid = threadIdx.x;
    int C = (nP + 1023) >> 10;
    int base = tid * C;
    int v[8]; int tot = 0;
    for (int j = 0; j < C; ++j) { v[j] = (base + j < nP) ? partial[base + j] : 0; tot += v[j]; }
    s[tid] = tot; __syncthreads();
    for (int off = 1; off < 1024; off <<= 1) {
        int t = (tid >= off) ? s[tid - off] : 0;
        __syncthreads(); s[tid] += t; __syncthreads();
    }
    int run = s[tid] - tot;
    for (int j = 0; j < C; ++j) { if (base + j < nP) { int tmp = v[j]; partial[base + j] = run; run += tmp; } }
}

// Level C: add block bases; extract bucketStart.
__global__ void k_scanC(int* __restrict__ data, const int* __restrict__ partial,
                        int* __restrict__ bucketStart, int M, int HB, int B, int E) {
    int f = blockIdx.x * 256 + threadIdx.x;
    if (f < M) {
        int val = data[f] + partial[f >> 8];
        data[f] = val;
        int q = f / HB;
        if (f - q * HB == 0) bucketStart[q] = val;
    }
    if (f == 0) bucketStart[B] = E;
}

// Partition: pos = scanned[bucket][block] + LDS-atomic rank.
// part[pos] = src | (dstLocal << 20)   (requires N < 2^20).
__launch_bounds__(256)
__global__ void k_part(const void* e, const int* __restrict__ histT,
                       int* __restrict__ part, const int* flags,
                       int E, int B, int HB) {
    __shared__ int lcur[1024];
    int tid = threadIdx.x;
    int is64 = flags[0];
    for (int f = tid; f < B; f += 256)
        lcur[f] = histT[(long long)f * HB + blockIdx.x];
    __syncthreads();
    int base = blockIdx.x * 4096;
    #pragma unroll
    for (int k = 0; k < 16; ++k) {
        int i = base + k * 256 + tid;
        if (i < E) {
            int s = edgeIdx(e, i, is64);
            int d = edgeIdx(e, (long long)E + i, is64);
            int pos = atomicAdd(&lcur[d >> 7], 1);   // LDS atomic
            part[pos] = s | ((d & 127) << 20);
        }
    }
}

// Block-per-bucket second sort: LDS 128-counter hist + LDS-rank scatter ->
// fully dst-sorted srcSorted[]; write start[node] and dinv[node].
__launch_bounds__(256)
__global__ void k_sort2(const int* __restrict__ part, const int* __restrict__ bucketStart,
                        int* __restrict__ srcSorted, int* __restrict__ start,
                        float* __restrict__ dinv, int N, int B) {
    __shared__ int cnt[128];
    __shared__ int basel[128];
    __shared__ int cur[128];
    int tid = threadIdx.x, b = blockIdx.x;
    if (tid < 128) cnt[tid] = 0;
    __syncthreads();
    int lo = bucketStart[b], hi = bucketStart[b + 1];
    for (int idx = lo + tid; idx < hi; idx += 256)
        atomicAdd(&cnt[(part[idx] >> 20) & 127], 1);
    __syncthreads();
    if (tid == 0) {
        int run = lo;
        for (int j = 0; j < 128; ++j) { basel[j] = run; run += cnt[j]; }
    }
    __syncthreads();
    if (tid < 128) {
        cur[tid] = basel[tid];
        int node = b * 128 + tid;
        if (node < N) {
            start[node] = basel[tid];
            dinv[node] = rsqrtf((float)(cnt[tid] + 1));  // +1 self-loop
        }
    }
    if (b == 0 && tid == 0) start[N] = bucketStart[B];  // = E
    __syncthreads();
    for (int idx = lo + tid; idx < hi; idx += 256) {
        int pw = part[idx];
        int pos = atomicAdd(&cur[(pw >> 20) & 127], 1);  // LDS atomic w/ return
        srcSorted[pos] = pw & 0xFFFFF;
    }
}

// hb[row][lane] = bf16( (x@W1)[row][lane] * dinv[row] ) — src-norm folded.
// NOTE: hb aliases part[] — runs after k_sort2 consumed part.
__launch_bounds__(256)
__global__ void k_gemm(const void* x, const void* W1, const float* __restrict__ dinv,
                       unsigned short* __restrict__ hb, const int* flags, int N) {
    __shared__ float Wl[128 * 64];   // 32 KB
    __shared__ float xr[4][128];
    int tid = threadIdx.x;
    int isbf = flags[1];
    for (int idx = tid; idx < 128 * 64; idx += 256) Wl[idx] = loadF(W1, idx, isbf);
    int w = tid >> 6, lane = tid & 63;
    for (int rb = blockIdx.x * 4; rb < N; rb += gridDim.x * 4) {
        int row = rb + w;
        bool active = row < N;
        __syncthreads();
        if (active) {
            if (isbf) {
                unsigned int wv = ((const unsigned int*)x)[(long long)row * 64 + lane];
                xr[w][2 * lane]     = bf2f((unsigned short)(wv & 0xffffu));
                xr[w][2 * lane + 1] = bf2f((unsigned short)(wv >> 16));
            } else {
                xr[w][lane]      = ((const float*)x)[(long long)row * 128 + lane];
                xr[w][lane + 64] = ((const float*)x)[(long long)row * 128 + 64 + lane];
            }
        }
        __syncthreads();
        if (active) {
            float acc = 0.f;
            #pragma unroll
            for (int k = 0; k < 128; ++k)
                acc += xr[w][k] * Wl[k * 64 + lane];
            hb[(long long)row * 64 + lane] = f2bf(acc * dinv[row]);
        }
    }
}

// Layer-1 aggregation + epilogue, wave-per-node, register accumulation.
// hb has dinv[src] folded. acc = hb[node] + Σ hb[src]; v = acc*di + b1.
// (Self term: hb[node]*di = h*di^2 — correct. R7 bug was an extra *di here.)
__launch_bounds__(256)
__global__ void k_agg1(const unsigned short* __restrict__ hb,
                       const float* __restrict__ dinv,
                       const int* __restrict__ start,
                       const int* __restrict__ srcSorted,
                       const void* b1, const void* W2, float* __restrict__ sbuf2,
                       const int* flags, int N) {
    int lane = threadIdx.x & 63;
    int node = (blockIdx.x * blockDim.x + threadIdx.x) >> 6;
    if (node >= N) return;
    int isbf = flags[1];
    float di = dinv[node];
    int base = start[node], cnt = start[node + 1] - base;
    float acc = bf2f(hb[(long long)node * 64 + lane]);  // self-loop: *di in epilogue
    for (int c = 0; c < cnt; c += 64) {
        int t = c + lane;
        int sidx = (t < cnt) ? srcSorted[base + t] : 0;
        int m = cnt - c; if (m > 64) m = 64;
        int t2 = 0;
        for (; t2 + 8 <= m; t2 += 8) {
            int s0 = __shfl(sidx, t2 + 0), s1 = __shfl(sidx, t2 + 1);
            int s2 = __shfl(sidx, t2 + 2), s3 = __shfl(sidx, t2 + 3);
            int s4 = __shfl(sidx, t2 + 4), s5 = __shfl(sidx, t2 + 5);
            int s6 = __shfl(sidx, t2 + 6), s7 = __shfl(sidx, t2 + 7);
            unsigned short v0 = hb[(long long)s0 * 64 + lane];
            unsigned short v1 = hb[(long long)s1 * 64 + lane];
            unsigned short v2 = hb[(long long)s2 * 64 + lane];
            unsigned short v3 = hb[(long long)s3 * 64 + lane];
            unsigned short v4 = hb[(long long)s4 * 64 + lane];
            unsigned short v5 = hb[(long long)s5 * 64 + lane];
            unsigned short v6 = hb[(long long)s6 * 64 + lane];
            unsigned short v7 = hb[(long long)s7 * 64 + lane];
            acc += bf2f(v0); acc += bf2f(v1); acc += bf2f(v2); acc += bf2f(v3);
            acc += bf2f(v4); acc += bf2f(v5); acc += bf2f(v6); acc += bf2f(v7);
        }
        for (; t2 < m; ++t2) {
            int s0 = __shfl(sidx, t2);
            acc += bf2f(hb[(long long)s0 * 64 + lane]);
        }
    }
    float v = acc * di + loadF(b1, lane, isbf);
    v = fmaxf(v, 0.f);
    float p = v * loadF(W2, lane, isbf);
    #pragma unroll
    for (int o = 32; o >= 1; o >>= 1) p += __shfl_xor(p, o);
    if (lane == 0) sbuf2[node] = p * di;
}

// Layer-2: out[i] = (sum_src sbuf2[src] + sbuf2[i]) * dinv[i] + b2.
__launch_bounds__(256)
__global__ void k_agg2(const float* __restrict__ sbuf2, const float* __restrict__ dinv,
                       const int* __restrict__ start,
                       const int* __restrict__ srcSorted,
                       const void* b2, void* out, const int* flags, int N) {
    int lane = threadIdx.x & 63;
    int node = (blockIdx.x * blockDim.x + threadIdx.x) >> 6;
    if (node >= N) return;
    int isbf = flags[1];
    float di = dinv[node];
    int base = start[node], cnt = start[node + 1] - base;
    float part = 0.f;
    for (int t = lane; t < cnt; t += 64) part += sbuf2[srcSorted[base + t]];
    #pragma unroll
    for (int o = 32; o >= 1; o >>= 1) part += __shfl_xor(part, o);
    if (lane == 0) {
        float o_ = (part + sbuf2[node]) * di + loadF(b2, 0, isbf);
        if (isbf) ((unsigned short*)out)[node] = f2bf(o_);
        else      ((float*)out)[node] = o_;
    }
}

extern "C" void kernel_launch(void* const* d_in, const int* in_sizes, int n_in,
                              void* d_out, int out_size, void* d_ws, size_t ws_size,
                              hipStream_t stream) {
    const void* x  = d_in[0];
    const void* e  = d_in[1];
    const void* W1 = d_in[2];
    const void* b1 = d_in[3];
    const void* W2 = d_in[4];
    const void* b2 = d_in[5];
    int N = in_sizes[0] / 128;     // 100000
    int E = in_sizes[1] / 2;       // 3200000
    int B  = (N + 127) / 128;      // 782 buckets (<=1024)
    int HB = (E + 4095) / 4096;    // 782 hist blocks
    int M  = B * HB;               // 611,524
    int nP = (M + 255) / 256;      // 2389 (<=8192)
    int NB = B * 128;              // 100,096 padded nodes
    int EP = ((E + 255) / 256) * 256;

    // Workspace (~29.5 MB; 40.4 MB proven safe, 52.8 MB crashes):
    int*   wsI         = (int*)d_ws;
    int*   flags       = wsI;                              // 256
    int*   histT       = wsI + 256;                        // M rounded
    int*   partial     = histT + ((M + 255) / 256) * 256;  // nP rounded
    int*   bucketStart = partial + ((nP + 255) / 256) * 256;  // B+1 -> 1040
    float* dinv        = (float*)(bucketStart + 1040);     // NB
    float* sbuf2       = dinv + NB;                        // NB
    int*   start       = (int*)(sbuf2 + NB);               // NB + 256
    int*   srcSorted   = start + NB + 256;                 // EP
    int*   part        = srcSorted + EP;                   // EP (12.8 MB)
    unsigned short* hb = (unsigned short*)part;            // N*64 bf16, ALIASES part

    hipLaunchKernelGGL(k_detect, dim3(1), dim3(64), 0, stream, e, x, flags);
    hipLaunchKernelGGL(k_hist, dim3(HB), dim3(256), 0, stream, e, histT, flags, E, B, HB);
    hipLaunchKernelGGL(k_scanA, dim3(nP), dim3(256), 0, stream, histT, partial, M);
    hipLaunchKernelGGL(k_scanB, dim3(1), dim3(1024), 0, stream, partial, nP);
    hipLaunchKernelGGL(k_scanC, dim3(nP), dim3(256), 0, stream,
                       histT, partial, bucketStart, M, HB, B, E);
    hipLaunchKernelGGL(k_part, dim3(HB), dim3(256), 0, stream, e, histT, part, flags, E, B, HB);
    hipLaunchKernelGGL(k_sort2, dim3(B), dim3(256), 0, stream,
                       part, bucketStart, srcSorted, start, dinv, N, B);
    hipLaunchKernelGGL(k_gemm, dim3(2048), dim3(256), 0, stream, x, W1, dinv, hb, flags, N);
    hipLaunchKernelGGL(k_agg1, dim3((N + 3) / 4), dim3(256), 0, stream,
                       hb, dinv, start, srcSorted, b1, W2, sbuf2, flags, N);
    hipLaunchKernelGGL(k_agg2, dim3((N + 3) / 4), dim3(256), 0, stream,
                       sbuf2, dinv, start, srcSorted, b2, d_out, flags, N);
}